// Round 2
// baseline (777.804 us; speedup 1.0000x reference)
//
#include <hip/hip_runtime.h>
#include <hip/hip_cooperative_groups.h>

namespace cg = cooperative_groups;

// CapsNet dynamic routing — single fused cooperative kernel + prep_w.
//   prep_w: W fp32 -> Wy (s-GEMM frag order), WTd (u-GEMM frag order)
//   kfused: grid 256 (1 block/CU, cooperative), block 1024 (16 waves).
//     Block b: x[b] fp32 -> LDS f16 (frag order) ONCE; routing logits b
//     live in registers across all 3 iterations (breg += delta each iter).
//     Per iteration:
//       batch role  : [delta-GEMM from LDS x + staged u] softmax, y-GEMM,
//                     y16/csum -> global, grid.sync()
//       k2 role     : (jb=b&31, chunk=(b>>5)*32) stage y16 chunk, s-GEMM
//                     (MFMA, W from L2) + bias*csum, squash, then either
//                     vout (final) or u-GEMM -> u16 + vb, grid.sync()
//     5 grid syncs total; y16/u16/csum/vb are the only HBM round-trips.

#define BSZ 256

typedef _Float16 f16x8 __attribute__((ext_vector_type(8)));
typedef float f32x4 __attribute__((ext_vector_type(4)));

// ---------------------------------------------------------------------------
// prep_w: grid 32 (block=j), block 256.
// Wy  f16x8 idx (per j, 2048 vecs): kt*256 + d*4 + quad   (kt=c>>5, e=c&7)
// WTd f16x8 idx (per j, 2048 vecs): kt*1024 + cc*4 + quad (kt=d>>5, e=d&7)
// ---------------------------------------------------------------------------
__global__ __launch_bounds__(256) void prep_w(
    const float* __restrict__ W,     // [32*64][256]
    _Float16* __restrict__ Wy,
    _Float16* __restrict__ WTd)
{
  __shared__ __align__(16) float Wsh[64 * 260];
  const int j = blockIdx.x, t = threadIdx.x;

  #pragma unroll
  for (int k = 0; k < 16; ++k) {
    const int q = k * 256 + t;
    const int row = q >> 6, c4 = (q & 63) * 4;
    *reinterpret_cast<f32x4*>(&Wsh[row * 260 + c4]) =
        *reinterpret_cast<const f32x4*>(&W[((size_t)j * 64 + row) * 256 + c4]);
  }
  __syncthreads();

  {
    const int d = t & 63, quad = t >> 6;
    f16x8* out = reinterpret_cast<f16x8*>(Wy) + (size_t)j * 2048;
    #pragma unroll
    for (int kt = 0; kt < 8; ++kt) {
      const int c0 = kt * 32 + quad * 8;
      f16x8 h;
      #pragma unroll
      for (int e = 0; e < 8; ++e) h[e] = (_Float16)Wsh[d * 260 + c0 + e];
      out[kt * 256 + d * 4 + quad] = h;
    }
  }
  {
    const int cc = t;
    f16x8* out = reinterpret_cast<f16x8*>(WTd) + (size_t)j * 2048;
    #pragma unroll
    for (int h8 = 0; h8 < 8; ++h8) {
      const int kt = h8 >> 2, quad = h8 & 3;
      f16x8 h;
      #pragma unroll
      for (int e = 0; e < 8; ++e)
        h[e] = (_Float16)Wsh[(h8 * 8 + e) * 260 + cc];
      out[kt * 1024 + cc * 4 + quad] = h;
    }
  }
}

// ---------------------------------------------------------------------------
// kfused.
// xs (LDS) layout, f16x8 vec idx: kk*1024 + c*4 + quad
//   (kk = i>>5, quad = (i>>3)&3, elem e = i&7); element (c,i) at f16 offset
//   F(c,i) = (i>>5)*8192 + c*32 + ((i>>3)&3)*8 + (i&7)
// y-GEMM B-frag:  vec[kk*1024 + ii*4 + quad]   (b128, conflict-free)
// delta B-frag:   xs[F(c0+e, ii)] e=0..7       (u16 strided, ~4-way)
// ---------------------------------------------------------------------------
__global__ __launch_bounds__(1024, 4) void kfused(
    const float* __restrict__ x,        // [b][c][i] fp32
    const _Float16* __restrict__ Wy,
    const _Float16* __restrict__ WTd,
    const float* __restrict__ bias,     // [32*64]
    const float* __restrict__ b_init,   // [b][j][i]
    _Float16* __restrict__ y16,         // [b][j][c]
    _Float16* __restrict__ u16,         // [b][j][c]
    float* __restrict__ csum_ws,        // [b][j]
    float* __restrict__ vb_ws,          // [b][j]
    float* __restrict__ vout)           // [b][j][d]
{
  __shared__ __align__(16) _Float16 xs[65536];     // 128 KiB: x[b] f16 frags
  __shared__ __align__(16) _Float16 SB[32 * 264];  // u / cs / y-repack / ysh
  __shared__ __align__(16) _Float16 vsh[32 * 72];
  __shared__ float vbs[32];
  __shared__ float csumsh[32];
  __shared__ float n2sh[32];
  __shared__ float vbsh[32];
  __shared__ float csums[32];

  cg::grid_group grid = cg::this_grid();

  const int b = blockIdx.x, t = threadIdx.x;
  const int w = t >> 6, lane = t & 63, l15 = lane & 15, quad = lane >> 4;
  const int ii = w * 16 + l15;
  const int jb = b & 31, b0 = (b >> 5) * 32;   // k2-role coordinates

  // ---- routing logits live in registers for the whole kernel ----
  float breg[2][4];
  {
    const float* bp = b_init + (size_t)b * 8192;
    #pragma unroll
    for (int mt = 0; mt < 2; ++mt)
      #pragma unroll
      for (int rr = 0; rr < 4; ++rr)
        breg[mt][rr] = bp[(mt * 16 + quad * 4 + rr) * 256 + ii];
  }

  // ---- convert x fp32 -> LDS f16 (frag order); 16 loads in flight ----
  {
    const float* xb = x + (size_t)b * 65536;
    f32x4 v[2][4][2];
    #pragma unroll
    for (int q = 0; q < 2; ++q) {
      const int p = q * 1024 + t;
      const int i8 = (p & 31) * 8, c4 = (p >> 5) * 4;
      #pragma unroll
      for (int s = 0; s < 4; ++s) {
        v[q][s][0] = *reinterpret_cast<const f32x4*>(&xb[(c4 + s) * 256 + i8]);
        v[q][s][1] = *reinterpret_cast<const f32x4*>(&xb[(c4 + s) * 256 + i8 + 4]);
      }
    }
    #pragma unroll
    for (int q = 0; q < 2; ++q) {
      const int p = q * 1024 + t;
      const int i8 = (p & 31) * 8, c4 = (p >> 5) * 4;
      const int kk = i8 >> 5, qd = (i8 >> 3) & 3;
      #pragma unroll
      for (int s = 0; s < 4; ++s) {
        f16x8 h;
        #pragma unroll
        for (int e = 0; e < 4; ++e) {
          h[e] = (_Float16)v[q][s][0][e];
          h[4 + e] = (_Float16)v[q][s][1][e];
        }
        *reinterpret_cast<f16x8*>(&xs[(kk * 1024 + (c4 + s) * 4 + qd) * 8]) = h;
      }
    }
  }

  for (int it = 0; it < 3; ++it) {
    // ================= routing phase (batch role b) =================
    if (it > 0) {
      const f16x8* ug = reinterpret_cast<const f16x8*>(u16 + (size_t)b * 8192);
      *reinterpret_cast<f16x8*>(&SB[(t >> 5) * 264 + (t & 31) * 8]) = ug[t];
      if (t < 32) vbs[t] = vb_ws[b * 32 + t];
    }
    if (t < 32) csumsh[t] = 0.f;
    __syncthreads();  // xs/SB/vbs staged; csumsh zeroed

    if (it > 0) {
      // delta-GEMM: D[j, ii] = sum_c u[j,c] x[c,ii], all from LDS
      const int xbase = ((ii >> 5) * 1024 + ((ii >> 3) & 3)) * 8 + (ii & 7);
      f32x4 acc0 = (f32x4){0.f, 0.f, 0.f, 0.f};
      f32x4 acc1 = (f32x4){0.f, 0.f, 0.f, 0.f};
      #pragma unroll
      for (int kk = 0; kk < 8; ++kk) {
        const int ko = kk * 32 + quad * 8;
        f16x8 bf;
        #pragma unroll
        for (int e = 0; e < 8; ++e)
          bf[e] = xs[xbase + (ko + e) * 32];   // x^T frag: strided u16 reads
        f16x8 a0 = *reinterpret_cast<const f16x8*>(&SB[l15 * 264 + ko]);
        f16x8 a1 = *reinterpret_cast<const f16x8*>(&SB[(16 + l15) * 264 + ko]);
        acc0 = __builtin_amdgcn_mfma_f32_16x16x32_f16(a0, bf, acc0, 0, 0, 0);
        acc1 = __builtin_amdgcn_mfma_f32_16x16x32_f16(a1, bf, acc1, 0, 0, 0);
      }
      #pragma unroll
      for (int rr = 0; rr < 4; ++rr) {
        const int j0 = quad * 4 + rr;
        breg[0][rr] += acc0[rr] + vbs[j0];
        breg[1][rr] += acc1[rr] + vbs[16 + j0];
      }
      __syncthreads();  // SB u-frag reads complete before softmax overwrites
    }

    // softmax over j (registers + shfl)
    float cf[2][4];
    {
      float m = breg[0][0];
      #pragma unroll
      for (int mt = 0; mt < 2; ++mt)
        #pragma unroll
        for (int rr = 0; rr < 4; ++rr) m = fmaxf(m, breg[mt][rr]);
      m = fmaxf(m, __shfl_xor(m, 16));
      m = fmaxf(m, __shfl_xor(m, 32));
      float s = 0.f;
      #pragma unroll
      for (int mt = 0; mt < 2; ++mt)
        #pragma unroll
        for (int rr = 0; rr < 4; ++rr) {
          float e = __expf(breg[mt][rr] - m);
          cf[mt][rr] = e; s += e;
        }
      s += __shfl_xor(s, 16);
      s += __shfl_xor(s, 32);
      const float rinv = 1.f / s;
      #pragma unroll
      for (int mt = 0; mt < 2; ++mt)
        #pragma unroll
        for (int rr = 0; rr < 4; ++rr) {
          const float cv = cf[mt][rr] * rinv;
          cf[mt][rr] = cv;
          SB[(mt * 16 + quad * 4 + rr) * 264 + ii] = (_Float16)cv;
        }
    }
    __syncthreads();  // cs (=SB) visible

    // csum[j]
    #pragma unroll
    for (int mt = 0; mt < 2; ++mt)
      #pragma unroll
      for (int rr = 0; rr < 4; ++rr) {
        float pj = cf[mt][rr];
        pj += __shfl_xor(pj, 1);
        pj += __shfl_xor(pj, 2);
        pj += __shfl_xor(pj, 4);
        pj += __shfl_xor(pj, 8);
        if (l15 == 0) atomicAdd(&csumsh[mt * 16 + quad * 4 + rr], pj);
      }

    // y[j,c] = sum_i c[j,i] * x[c,i]  (both operands in LDS)
    f32x4 acy0 = (f32x4){0.f, 0.f, 0.f, 0.f};
    f32x4 acy1 = (f32x4){0.f, 0.f, 0.f, 0.f};
    #pragma unroll
    for (int kk = 0; kk < 8; ++kk) {
      const int ko = kk * 32 + quad * 8;
      f16x8 bf =
          *reinterpret_cast<const f16x8*>(&xs[(kk * 1024 + ii * 4 + quad) * 8]);
      f16x8 a0 = *reinterpret_cast<const f16x8*>(&SB[l15 * 264 + ko]);
      f16x8 a1 = *reinterpret_cast<const f16x8*>(&SB[(16 + l15) * 264 + ko]);
      acy0 = __builtin_amdgcn_mfma_f32_16x16x32_f16(a0, bf, acy0, 0, 0, 0);
      acy1 = __builtin_amdgcn_mfma_f32_16x16x32_f16(a1, bf, acy1, 0, 0, 0);
    }
    __syncthreads();  // all cs reads done before repack overwrites SB

    #pragma unroll
    for (int rr = 0; rr < 4; ++rr) {
      SB[(quad * 4 + rr) * 264 + ii] = (_Float16)acy0[rr];
      SB[(16 + quad * 4 + rr) * 264 + ii] = (_Float16)acy1[rr];
    }
    __syncthreads();
    *reinterpret_cast<f16x8*>(&y16[(size_t)b * 8192 + (t >> 5) * 256 + (t & 31) * 8]) =
        *reinterpret_cast<const f16x8*>(&SB[(t >> 5) * 264 + (t & 31) * 8]);
    if (t < 32) csum_ws[b * 32 + t] = csumsh[t];

    __threadfence();
    grid.sync();

    // ================= k2 phase (role jb, batches b0..b0+31) =================
    *reinterpret_cast<f16x8*>(&SB[(t >> 5) * 264 + (t & 31) * 8]) =
        *reinterpret_cast<const f16x8*>(
            &y16[(size_t)(b0 + (t >> 5)) * 8192 + jb * 256 + (t & 31) * 8]);
    if (t < 32) {
      csums[t] = csum_ws[(b0 + t) * 32 + jb];
      n2sh[t] = 0.f;
      vbsh[t] = 0.f;
    }
    __syncthreads();

    const int mtk = w & 1;
    const int d = (w >> 1) * 16 + l15;   // meaningful for w<8 only
    float sv[4];
    float biasd = 0.f;
    if (w < 8) {
      const f16x8* Wg8 = reinterpret_cast<const f16x8*>(Wy) + (size_t)jb * 2048;
      f32x4 sacc = (f32x4){0.f, 0.f, 0.f, 0.f};
      #pragma unroll
      for (int kt = 0; kt < 8; ++kt) {
        const int ko = kt * 32 + quad * 8;
        f16x8 a =
            *reinterpret_cast<const f16x8*>(&SB[(mtk * 16 + l15) * 264 + ko]);
        f16x8 bf = Wg8[kt * 256 + d * 4 + quad];   // coalesced (L2)
        sacc = __builtin_amdgcn_mfma_f32_16x16x32_f16(a, bf, sacc, 0, 0, 0);
      }
      biasd = bias[jb * 64 + d];
      #pragma unroll
      for (int rr = 0; rr < 4; ++rr) {
        sv[rr] = sacc[rr] + biasd * csums[mtk * 16 + quad * 4 + rr];
        float p = sv[rr] * sv[rr];
        p += __shfl_xor(p, 1);
        p += __shfl_xor(p, 2);
        p += __shfl_xor(p, 4);
        p += __shfl_xor(p, 8);
        if (l15 == 0) atomicAdd(&n2sh[mtk * 16 + quad * 4 + rr], p);
      }
    }
    __syncthreads();

    if (it == 2) {
      if (w < 8) {
        #pragma unroll
        for (int rr = 0; rr < 4; ++rr) {
          const float n2 = n2sh[mtk * 16 + quad * 4 + rr];
          const float sc = sqrtf(n2) / (1.f + n2);
          vout[((size_t)(b0 + mtk * 16 + quad * 4 + rr) * 32 + jb) * 64 + d] =
              sv[rr] * sc;
        }
      }
      // final: no trailing sync, loop exits next
    } else {
      if (w < 8) {
        #pragma unroll
        for (int rr = 0; rr < 4; ++rr) {
          const float n2 = n2sh[mtk * 16 + quad * 4 + rr];
          const float sc = sqrtf(n2) / (1.f + n2);
          const float vvr = sv[rr] * sc;
          vsh[(mtk * 16 + quad * 4 + rr) * 72 + d] = (_Float16)vvr;
          float p = vvr * biasd;
          p += __shfl_xor(p, 1);
          p += __shfl_xor(p, 2);
          p += __shfl_xor(p, 4);
          p += __shfl_xor(p, 8);
          if (l15 == 0) atomicAdd(&vbsh[mtk * 16 + quad * 4 + rr], p);
        }
      }
      __syncthreads();   // vsh/vbsh complete; ysh reads done -> SB reusable
      if (t < 32) vb_ws[(b0 + t) * 32 + jb] = vbsh[t];

      // u-GEMM, all 16 waves: (mtk, ntu = (w>>1)*2 + q)
      const f16x8* WT8 = reinterpret_cast<const f16x8*>(WTd) + (size_t)jb * 2048;
      #pragma unroll
      for (int q = 0; q < 2; ++q) {
        const int ntu = (w >> 1) * 2 + q;
        const int ccn = ntu * 16 + l15;
        f32x4 ua = (f32x4){0.f, 0.f, 0.f, 0.f};
        #pragma unroll
        for (int kt = 0; kt < 2; ++kt) {
          const int ko = kt * 32 + quad * 8;
          f16x8 a =
              *reinterpret_cast<const f16x8*>(&vsh[(mtk * 16 + l15) * 72 + ko]);
          f16x8 bf = WT8[kt * 1024 + ccn * 4 + quad];   // coalesced (L2)
          ua = __builtin_amdgcn_mfma_f32_16x16x32_f16(a, bf, ua, 0, 0, 0);
        }
        #pragma unroll
        for (int rr = 0; rr < 4; ++rr)
          SB[(mtk * 16 + quad * 4 + rr) * 264 + ccn] = (_Float16)ua[rr];
      }
      __syncthreads();
      *reinterpret_cast<f16x8*>(
          &u16[(size_t)(b0 + (t >> 5)) * 8192 + jb * 256 + (t & 31) * 8]) =
          *reinterpret_cast<const f16x8*>(&SB[(t >> 5) * 264 + (t & 31) * 8]);

      __threadfence();
      grid.sync();
    }
  }
}

// ---------------------------------------------------------------------------
extern "C" void kernel_launch(void* const* d_in, const int* in_sizes, int n_in,
                              void* d_out, int out_size, void* d_ws, size_t ws_size,
                              hipStream_t stream) {
  (void)in_sizes; (void)n_in; (void)out_size; (void)ws_size;
  const float* x      = (const float*)d_in[0];
  const float* W      = (const float*)d_in[1];
  const float* bias   = (const float*)d_in[2];
  const float* b_init = (const float*)d_in[3];
  char* ws = (char*)d_ws;

  _Float16* Wy   = (_Float16*)(ws);                             // 1 MiB
  _Float16* WTd  = (_Float16*)(ws + (1u << 20));                // 1 MiB
  _Float16* y16  = (_Float16*)(ws + (2u << 20));                // 4 MiB
  _Float16* u16  = (_Float16*)(ws + (6u << 20));                // 4 MiB
  float*    csum = (float*)(ws + (10u << 20));                  // 32 KiB
  float*    vb   = (float*)(ws + (10u << 20) + (64u << 10));    // 32 KiB
  float*    vout = (float*)d_out;

  prep_w<<<32, 256, 0, stream>>>(W, Wy, WTd);

  void* kargs[] = {&x, &Wy, &WTd, &bias, &b_init, &y16, &u16, &csum, &vb, &vout};
  hipLaunchCooperativeKernel((const void*)kfused, dim3(BSZ), dim3(1024),
                             kargs, 0, stream);
}

// Round 3
// 175.435 us; speedup vs baseline: 4.4336x; 4.4336x over previous
//
#include <hip/hip_runtime.h>

// CapsNet dynamic routing — 7 launches, i-split kA (2 blocks/CU).
//   prep_w: W fp32 -> Wy (s-GEMM frag order), WTd (u-GEMM frag order)
//   kA: grid 512 = (batch b, half h), block 512 (8 waves). Block owns i
//     columns [h*128, h*128+128). x half-batch lives in LDS (64 KiB frag
//     order); mode 0 converts fp32 x -> LDS + xs_g; modes 1/2 restage via
//     global_load_lds. delta-GEMM reads u A-frags direct from global
//     (L1/L2-resident). Softmax per column (regs+shfl). Partial y + csum
//     written per half (y16a/y16b, csumA/csumB); b2 fp32 checkpoint after
//     iter 2 keeps iter 3 a single delta pass.
//   k2: grid 256 = (j, 32-batch chunk), block 512 (8 waves). Stages both
//     y halves, chains 2 MFMAs per kt into one accumulator. W frags
//     prefetched to registers. squash, then u-GEMM -> u16 (+vb) or vout.

#define BSZ 256

typedef _Float16 f16x8 __attribute__((ext_vector_type(8)));
typedef float f32x4 __attribute__((ext_vector_type(4)));

__device__ __forceinline__ void gload_lds16(const void* g, void* l) {
  __builtin_amdgcn_global_load_lds(
      (const __attribute__((address_space(1))) void*)g,
      (__attribute__((address_space(3))) void*)l, 16, 0, 0);
}

// ---------------------------------------------------------------------------
// prep_w: grid 32 (block=j), block 256.
// Wy  f16x8 idx (per j, 2048 vecs): kt*256 + d*4 + quad   (kt=c>>5, e=c&7)
// WTd f16x8 idx (per j, 2048 vecs): kt*1024 + cc*4 + quad (kt=d>>5, e=d&7)
// ---------------------------------------------------------------------------
__global__ __launch_bounds__(256) void prep_w(
    const float* __restrict__ W,     // [32*64][256]
    _Float16* __restrict__ Wy,
    _Float16* __restrict__ WTd)
{
  __shared__ __align__(16) float Wsh[64 * 260];
  const int j = blockIdx.x, t = threadIdx.x;

  #pragma unroll
  for (int k = 0; k < 16; ++k) {
    const int q = k * 256 + t;
    const int row = q >> 6, c4 = (q & 63) * 4;
    *reinterpret_cast<f32x4*>(&Wsh[row * 260 + c4]) =
        *reinterpret_cast<const f32x4*>(&W[((size_t)j * 64 + row) * 256 + c4]);
  }
  __syncthreads();

  {
    const int d = t & 63, quad = t >> 6;
    f16x8* out = reinterpret_cast<f16x8*>(Wy) + (size_t)j * 2048;
    #pragma unroll
    for (int kt = 0; kt < 8; ++kt) {
      const int c0 = kt * 32 + quad * 8;
      f16x8 hv;
      #pragma unroll
      for (int e = 0; e < 8; ++e) hv[e] = (_Float16)Wsh[d * 260 + c0 + e];
      out[kt * 256 + d * 4 + quad] = hv;
    }
  }
  {
    const int cc = t;
    f16x8* out = reinterpret_cast<f16x8*>(WTd) + (size_t)j * 2048;
    #pragma unroll
    for (int h8 = 0; h8 < 8; ++h8) {
      const int kt = h8 >> 2, quad = h8 & 3;
      f16x8 hv;
      #pragma unroll
      for (int e = 0; e < 8; ++e)
        hv[e] = (_Float16)Wsh[(h8 * 8 + e) * 260 + cc];
      out[kt * 1024 + cc * 4 + quad] = hv;
    }
  }
}

// ---------------------------------------------------------------------------
// kA: grid 512 (b = blockIdx>>1, h = blockIdx&1), block 512 (8 waves).
// xs (LDS, per half) f16x8 vec idx: kk*1024 + c*4 + quad
//   (kk = il>>5, quad = (il>>3)&3, elem e = il&7; il = local i 0..127)
//   element (c,il) at f16 offset (il>>5)*8192 + c*32 + ((il>>3)&3)*8 + (il&7)
// xs_g mirrors LDS content at [b*8192 + h*4096 + vec] (f16x8 units).
// y-GEMM B-frag:  vec[kk*1024 + c*4 + quad]   (b128, conflict-free)
// delta B-frag:   xs[xbase + (ko+e)*32]       (u16 strided, ~4-way)
// ---------------------------------------------------------------------------
__global__ __launch_bounds__(512) void kA(
    const float* __restrict__ x,        // [b][c][i] fp32 (mode 0)
    _Float16* __restrict__ xs_g,        // frag-ordered f16 x mirror
    const _Float16* __restrict__ u,     // [b][j][c]  (modes 1,2)
    const float* __restrict__ vb,       // [b][j]     (modes 1,2)
    const float* __restrict__ bsrc,     // [b][j][i]  (b_init or b2)
    float* __restrict__ b2out,          // [b][j][i]  (mode 1 writes)
    _Float16* __restrict__ y16a,       // [b][j][c] partial, h=0
    _Float16* __restrict__ y16b,       // [b][j][c] partial, h=1
    float* __restrict__ csumA,          // [b][j] partial, h=0
    float* __restrict__ csumB,          // [b][j] partial, h=1
    int mode)
{
  __shared__ __align__(16) _Float16 xs[32768];     // 64 KiB: half-batch x
  __shared__ __align__(16) _Float16 cs[32 * 136];  // softmax out (8.5 KiB)
  __shared__ float vbs[32];
  __shared__ float csumsh[32];

  const int bh = blockIdx.x;
  const int b = bh >> 1, h = bh & 1;
  const int t = threadIdx.x;
  const int w = t >> 6, lane = t & 63, l15 = lane & 15, quad = lane >> 4;
  const int ii = w * 16 + l15;            // local column 0..127
  const int ig = h * 128 + ii;            // global i column
  const float* bp = bsrc + (size_t)b * 8192;

  float breg[2][4];

  if (mode == 0) {
    // ---- convert x[b][:, h-half] fp32 -> LDS xs + global xs_g ----
    const float* xb = x + (size_t)b * 65536 + h * 128;
    f16x8* xg = reinterpret_cast<f16x8*>(xs_g) + (size_t)b * 8192 + h * 4096;
    #pragma unroll
    for (int q = 0; q < 2; ++q) {
      const int p = q * 512 + t;
      const int i8 = (p & 15) * 8, c4 = (p >> 4) * 4;
      const int kk = i8 >> 5, qd = (i8 >> 3) & 3;
      f32x4 v[4][2];
      #pragma unroll
      for (int s = 0; s < 4; ++s) {
        v[s][0] = *reinterpret_cast<const f32x4*>(&xb[(c4 + s) * 256 + i8]);
        v[s][1] = *reinterpret_cast<const f32x4*>(&xb[(c4 + s) * 256 + i8 + 4]);
      }
      #pragma unroll
      for (int s = 0; s < 4; ++s) {
        f16x8 hv;
        #pragma unroll
        for (int e = 0; e < 4; ++e) {
          hv[e] = (_Float16)v[s][0][e];
          hv[4 + e] = (_Float16)v[s][1][e];
        }
        const int vi = kk * 1024 + (c4 + s) * 4 + qd;
        *reinterpret_cast<f16x8*>(&xs[vi * 8]) = hv;
        xg[vi] = hv;
      }
    }
  } else {
    // ---- restage xs_g half -> LDS (async, 16B/lane, linear dest) ----
    const f16x8* xg =
        reinterpret_cast<const f16x8*>(xs_g) + (size_t)b * 8192 + h * 4096;
    #pragma unroll
    for (int it8 = 0; it8 < 8; ++it8) {
      const int vi = it8 * 512 + t;
      gload_lds16(xg + vi, &xs[vi * 8]);
    }
    if (t < 32) vbs[t] = vb[b * 32 + t];
  }

  // hoisted routing-logit loads (overlap staging traffic)
  #pragma unroll
  for (int mt = 0; mt < 2; ++mt)
    #pragma unroll
    for (int rr = 0; rr < 4; ++rr)
      breg[mt][rr] = bp[(mt * 16 + quad * 4 + rr) * 256 + ig];

  if (t < 32) csumsh[t] = 0.f;
  __syncthreads();  // xs staged (vmcnt drained), vbs/csumsh ready

  if (mode != 0) {
    // ---- delta-GEMM: D[j, ig] = sum_c u[j,c] x[c,ig] ----
    // A-frags direct from global u (16 KB/batch, L1/L2-hit); B from LDS.
    const _Float16* ug = u + (size_t)b * 8192;
    const int xbase = (ii >> 5) * 8192 + ((ii >> 3) & 3) * 8 + (ii & 7);
    f32x4 acc0 = (f32x4){0.f, 0.f, 0.f, 0.f};
    f32x4 acc1 = (f32x4){0.f, 0.f, 0.f, 0.f};
    #pragma unroll
    for (int kk = 0; kk < 8; ++kk) {
      const int ko = kk * 32 + quad * 8;
      f16x8 bf;
      #pragma unroll
      for (int e = 0; e < 8; ++e)
        bf[e] = xs[xbase + (ko + e) * 32];   // x^T frag: strided u16 reads
      f16x8 a0 = *reinterpret_cast<const f16x8*>(&ug[l15 * 256 + ko]);
      f16x8 a1 = *reinterpret_cast<const f16x8*>(&ug[(16 + l15) * 256 + ko]);
      acc0 = __builtin_amdgcn_mfma_f32_16x16x32_f16(a0, bf, acc0, 0, 0, 0);
      acc1 = __builtin_amdgcn_mfma_f32_16x16x32_f16(a1, bf, acc1, 0, 0, 0);
    }
    #pragma unroll
    for (int rr = 0; rr < 4; ++rr) {
      const int j0 = quad * 4 + rr;
      breg[0][rr] += acc0[rr] + vbs[j0];
      breg[1][rr] += acc1[rr] + vbs[16 + j0];
    }
    if (mode == 1) {
      // checkpoint b2 = b_init + D0 + vb0 (fp32, bit-identical to recompute)
      float* bo = b2out + (size_t)b * 8192;
      #pragma unroll
      for (int mt = 0; mt < 2; ++mt)
        #pragma unroll
        for (int rr = 0; rr < 4; ++rr)
          bo[(mt * 16 + quad * 4 + rr) * 256 + ig] = breg[mt][rr];
    }
  }

  // ---- softmax over j (registers + shfl across quads/halves) ----
  float cf[2][4];
  {
    float m = breg[0][0];
    #pragma unroll
    for (int mt = 0; mt < 2; ++mt)
      #pragma unroll
      for (int rr = 0; rr < 4; ++rr) m = fmaxf(m, breg[mt][rr]);
    m = fmaxf(m, __shfl_xor(m, 16));
    m = fmaxf(m, __shfl_xor(m, 32));
    float s = 0.f;
    #pragma unroll
    for (int mt = 0; mt < 2; ++mt)
      #pragma unroll
      for (int rr = 0; rr < 4; ++rr) {
        float e = __expf(breg[mt][rr] - m);
        cf[mt][rr] = e; s += e;
      }
    s += __shfl_xor(s, 16);
    s += __shfl_xor(s, 32);
    const float rinv = 1.f / s;
    #pragma unroll
    for (int mt = 0; mt < 2; ++mt)
      #pragma unroll
      for (int rr = 0; rr < 4; ++rr) {
        const float cv = cf[mt][rr] * rinv;
        cf[mt][rr] = cv;
        cs[(mt * 16 + quad * 4 + rr) * 136 + ii] = (_Float16)cv;
      }
  }
  __syncthreads();  // cs visible

  // csum[j] partial (this half's 128 columns)
  #pragma unroll
  for (int mt = 0; mt < 2; ++mt)
    #pragma unroll
    for (int rr = 0; rr < 4; ++rr) {
      float pj = cf[mt][rr];
      pj += __shfl_xor(pj, 1);
      pj += __shfl_xor(pj, 2);
      pj += __shfl_xor(pj, 4);
      pj += __shfl_xor(pj, 8);
      if (l15 == 0) atomicAdd(&csumsh[mt * 16 + quad * 4 + rr], pj);
    }

  // ---- partial y[j,c] = sum_{i in half} c[j,i] x[c,i] ----
  // wave w covers c = w*32 + {0,16} + l15; kk 0..3 covers local i.
  f32x4 acy[2][2];
  #pragma unroll
  for (int mt = 0; mt < 2; ++mt)
    #pragma unroll
    for (int s = 0; s < 2; ++s)
      acy[mt][s] = (f32x4){0.f, 0.f, 0.f, 0.f};
  #pragma unroll
  for (int kk = 0; kk < 4; ++kk) {
    const int ko = kk * 32 + quad * 8;
    f16x8 a0 = *reinterpret_cast<const f16x8*>(&cs[l15 * 136 + ko]);
    f16x8 a1 = *reinterpret_cast<const f16x8*>(&cs[(16 + l15) * 136 + ko]);
    f16x8 bf0 = *reinterpret_cast<const f16x8*>(
        &xs[(kk * 1024 + (w * 32 + l15) * 4 + quad) * 8]);
    f16x8 bf1 = *reinterpret_cast<const f16x8*>(
        &xs[(kk * 1024 + (w * 32 + 16 + l15) * 4 + quad) * 8]);
    acy[0][0] = __builtin_amdgcn_mfma_f32_16x16x32_f16(a0, bf0, acy[0][0], 0, 0, 0);
    acy[0][1] = __builtin_amdgcn_mfma_f32_16x16x32_f16(a0, bf1, acy[0][1], 0, 0, 0);
    acy[1][0] = __builtin_amdgcn_mfma_f32_16x16x32_f16(a1, bf0, acy[1][0], 0, 0, 0);
    acy[1][1] = __builtin_amdgcn_mfma_f32_16x16x32_f16(a1, bf1, acy[1][1], 0, 0, 0);
  }
  __syncthreads();  // all xs/cs reads done -> xs reusable as y-repack stage

  _Float16* ysta = xs;   // [32 j][264] f16 staging
  #pragma unroll
  for (int mt = 0; mt < 2; ++mt)
    #pragma unroll
    for (int s = 0; s < 2; ++s)
      #pragma unroll
      for (int rr = 0; rr < 4; ++rr)
        ysta[(mt * 16 + quad * 4 + rr) * 264 + w * 32 + s * 16 + l15] =
            (_Float16)acy[mt][s][rr];
  __syncthreads();
  {
    _Float16* yo = (h ? y16b : y16a) + (size_t)b * 8192;
    #pragma unroll
    for (int p0 = 0; p0 < 2; ++p0) {
      const int p = p0 * 512 + t;
      const int row = p >> 5, co = (p & 31) * 8;
      *reinterpret_cast<f16x8*>(&yo[row * 256 + co]) =
          *reinterpret_cast<const f16x8*>(&ysta[row * 264 + co]);
    }
  }
  if (t < 32) (h ? csumB : csumA)[b * 32 + t] = csumsh[t];
}

// ---------------------------------------------------------------------------
// k2: grid 256 = 32 j x 8 chunks of 32 batches, block 512 (8 waves).
// ---------------------------------------------------------------------------
__global__ __launch_bounds__(512) void k2(
    const _Float16* __restrict__ Wy,
    const _Float16* __restrict__ WTd,
    const float* __restrict__ bias,
    const _Float16* __restrict__ y16a,  // [b][j][c] partial h=0
    const _Float16* __restrict__ y16b,  // [b][j][c] partial h=1
    const float* __restrict__ csumA,    // [b][j] partial
    const float* __restrict__ csumB,    // [b][j] partial
    _Float16* __restrict__ u16,         // [b][j][c] (target buffer)
    float* __restrict__ vb_ws,          // [b][j]
    float* __restrict__ vout,           // [b][j][d]
    int final_iter)
{
  __shared__ __align__(16) _Float16 ysh0[32 * 264];  // h=0 stage, u-repack
  __shared__ __align__(16) _Float16 ysh1[32 * 264];  // h=1 stage
  __shared__ __align__(16) _Float16 vsh[32 * 72];
  __shared__ float n2sh[32];
  __shared__ float vbsh[32];
  __shared__ float csums[32];

  const int jb = blockIdx.x & 31;
  const int b0 = (blockIdx.x >> 5) * 32;
  const int t = threadIdx.x;
  const int w = t >> 6, lane = t & 63, l15 = lane & 15, quad = lane >> 4;

  #pragma unroll
  for (int p0 = 0; p0 < 2; ++p0) {
    const int p = p0 * 512 + t;
    const int bs = p >> 5, co = (p & 31) * 8;
    const size_t gix = (size_t)(b0 + bs) * 8192 + jb * 256 + co;
    *reinterpret_cast<f16x8*>(&ysh0[bs * 264 + co]) =
        *reinterpret_cast<const f16x8*>(&y16a[gix]);
    *reinterpret_cast<f16x8*>(&ysh1[bs * 264 + co]) =
        *reinterpret_cast<const f16x8*>(&y16b[gix]);
  }
  if (t < 32) {
    csums[t] = csumA[(b0 + t) * 32 + jb] + csumB[(b0 + t) * 32 + jb];
    n2sh[t] = 0.f;
    vbsh[t] = 0.f;
  }
  __syncthreads();

  // ---- s-GEMM: wave w -> (mt = w&1, nt = w>>1); W prefetched ----
  const int mt = w & 1, nt = w >> 1;
  const int d = nt * 16 + l15;
  f16x8 wreg[8];
  {
    const f16x8* Wg8 = reinterpret_cast<const f16x8*>(Wy) + (size_t)jb * 2048;
    #pragma unroll
    for (int kt = 0; kt < 8; ++kt) wreg[kt] = Wg8[kt * 256 + d * 4 + quad];
  }
  f32x4 sacc = (f32x4){0.f, 0.f, 0.f, 0.f};
  #pragma unroll
  for (int kt = 0; kt < 8; ++kt) {
    const int ko = kt * 32 + quad * 8;
    f16x8 a0 = *reinterpret_cast<const f16x8*>(&ysh0[(mt * 16 + l15) * 264 + ko]);
    f16x8 a1 = *reinterpret_cast<const f16x8*>(&ysh1[(mt * 16 + l15) * 264 + ko]);
    sacc = __builtin_amdgcn_mfma_f32_16x16x32_f16(a0, wreg[kt], sacc, 0, 0, 0);
    sacc = __builtin_amdgcn_mfma_f32_16x16x32_f16(a1, wreg[kt], sacc, 0, 0, 0);
  }
  const float biasd = bias[jb * 64 + d];
  float sv[4];
  #pragma unroll
  for (int rr = 0; rr < 4; ++rr)
    sv[rr] = sacc[rr] + biasd * csums[mt * 16 + quad * 4 + rr];

  #pragma unroll
  for (int rr = 0; rr < 4; ++rr) {
    float p = sv[rr] * sv[rr];
    p += __shfl_xor(p, 1);
    p += __shfl_xor(p, 2);
    p += __shfl_xor(p, 4);
    p += __shfl_xor(p, 8);
    if (l15 == 0) atomicAdd(&n2sh[mt * 16 + quad * 4 + rr], p);
  }
  __syncthreads();

  float vv[4];
  #pragma unroll
  for (int rr = 0; rr < 4; ++rr) {
    const float n2 = n2sh[mt * 16 + quad * 4 + rr];
    const float sc = sqrtf(n2) / (1.f + n2);
    vv[rr] = sv[rr] * sc;
  }

  if (final_iter) {
    #pragma unroll
    for (int rr = 0; rr < 4; ++rr)
      vout[((size_t)(b0 + mt * 16 + quad * 4 + rr) * 32 + jb) * 64 + d] = vv[rr];
  } else {
    #pragma unroll
    for (int rr = 0; rr < 4; ++rr) {
      vsh[(mt * 16 + quad * 4 + rr) * 72 + d] = (_Float16)vv[rr];
      float p = vv[rr] * biasd;
      p += __shfl_xor(p, 1);
      p += __shfl_xor(p, 2);
      p += __shfl_xor(p, 4);
      p += __shfl_xor(p, 8);
      if (l15 == 0) atomicAdd(&vbsh[mt * 16 + quad * 4 + rr], p);
    }
    __syncthreads();   // vsh/vbsh complete; ysh reads done -> reuse ysh0
    if (t < 32) vb_ws[(b0 + t) * 32 + jb] = vbsh[t];

    // ---- u-GEMM: wave w -> (mt, ntu = (w>>1)*4 + q) ----
    const f16x8* WT8 = reinterpret_cast<const f16x8*>(WTd) + (size_t)jb * 2048;
    #pragma unroll
    for (int q = 0; q < 4; ++q) {
      const int ntu = (w >> 1) * 4 + q;
      const int cc = ntu * 16 + l15;
      f32x4 ua = (f32x4){0.f, 0.f, 0.f, 0.f};
      #pragma unroll
      for (int kt = 0; kt < 2; ++kt) {
        const int ko = kt * 32 + quad * 8;
        f16x8 a =
            *reinterpret_cast<const f16x8*>(&vsh[(mt * 16 + l15) * 72 + ko]);
        f16x8 bf = WT8[kt * 1024 + cc * 4 + quad];   // coalesced (L2)
        ua = __builtin_amdgcn_mfma_f32_16x16x32_f16(a, bf, ua, 0, 0, 0);
      }
      #pragma unroll
      for (int rr = 0; rr < 4; ++rr)
        ysh0[(mt * 16 + quad * 4 + rr) * 264 + cc] = (_Float16)ua[rr];
    }
    __syncthreads();
    // coalesced u16 write-out
    #pragma unroll
    for (int p0 = 0; p0 < 2; ++p0) {
      const int p = p0 * 512 + t;
      const int bs = p >> 5, co = (p & 31) * 8;
      *reinterpret_cast<f16x8*>(&u16[(size_t)(b0 + bs) * 8192 + jb * 256 + co]) =
          *reinterpret_cast<const f16x8*>(&ysh0[bs * 264 + co]);
    }
  }
}

// ---------------------------------------------------------------------------
extern "C" void kernel_launch(void* const* d_in, const int* in_sizes, int n_in,
                              void* d_out, int out_size, void* d_ws, size_t ws_size,
                              hipStream_t stream) {
  (void)in_sizes; (void)n_in; (void)out_size; (void)ws_size;
  const float* x      = (const float*)d_in[0];
  const float* W      = (const float*)d_in[1];
  const float* bias   = (const float*)d_in[2];
  const float* b_init = (const float*)d_in[3];
  char* ws = (char*)d_ws;

  _Float16* xs_g  = (_Float16*)(ws);                            // 32 MiB
  _Float16* y16a  = (_Float16*)(ws + (32u << 20));              // 4 MiB
  _Float16* y16b  = (_Float16*)(ws + (36u << 20));              // 4 MiB
  _Float16* u16a  = (_Float16*)(ws + (40u << 20));              // 4 MiB
  _Float16* u16b  = (_Float16*)(ws + (44u << 20));              // 4 MiB
  float*    b2    = (float*)(ws + (48u << 20));                 // 8 MiB
  _Float16* Wy    = (_Float16*)(ws + (56u << 20));              // 1 MiB
  _Float16* WTd   = (_Float16*)(ws + (57u << 20));              // 1 MiB
  float*    csumA = (float*)(ws + (58u << 20));                 // 32 KiB
  float*    csumB = (float*)(ws + (58u << 20) + (32u << 10));   // 32 KiB
  float*    vb0   = (float*)(ws + (58u << 20) + (64u << 10));   // 32 KiB
  float*    vb1   = (float*)(ws + (58u << 20) + (96u << 10));   // 32 KiB
  float*    vout  = (float*)d_out;

  prep_w<<<32, 256, 0, stream>>>(W, Wy, WTd);
  // iter 1: convert x, softmax(b_init), partial y
  kA<<<512, 512, 0, stream>>>(x, xs_g, u16a, vb0, b_init, b2,
                              y16a, y16b, csumA, csumB, 0);
  k2<<<256, 512, 0, stream>>>(Wy, WTd, bias, y16a, y16b, csumA, csumB,
                              u16a, vb0, vout, 0);
  // iter 2: b = b_init + D(u0)+vb0, checkpoint b2
  kA<<<512, 512, 0, stream>>>(x, xs_g, u16a, vb0, b_init, b2,
                              y16a, y16b, csumA, csumB, 1);
  k2<<<256, 512, 0, stream>>>(Wy, WTd, bias, y16a, y16b, csumA, csumB,
                              u16b, vb1, vout, 0);
  // iter 3: b = b2 + D(u1)+vb1 (single delta pass)
  kA<<<512, 512, 0, stream>>>(x, xs_g, u16b, vb1, b2, b2,
                              y16a, y16b, csumA, csumB, 2);
  k2<<<256, 512, 0, stream>>>(Wy, WTd, bias, y16a, y16b, csumA, csumB,
                              u16a, vb0, vout, 1);
}